// Round 1
// baseline (25.868 us; speedup 1.0000x reference)
//
#include <hip/hip_runtime.h>

// GATconv_72464688218548 — the reference's outputs are:
//   (adj, log_softmax(elu(gat_out), axis=1))
// with gat_out shape (N, NOUT) = (4096, 1). log_softmax over a singleton
// axis is identically zero (x - logsumexp(x) = x - x) for any finite x,
// so the second output is exactly zeros(4096) regardless of the GAT math.
// The first output is adj passed through unchanged.
//
// Therefore the whole op reduces to: d_out[0 : N*N] = adj (67 MB copy),
// d_out[N*N : N*N + N] = 0. Pure memory-bound: ~134 MB HBM traffic.

extern "C" void kernel_launch(void* const* d_in, const int* in_sizes, int n_in,
                              void* d_out, int out_size, void* d_ws, size_t ws_size,
                              hipStream_t stream) {
    const float* adj = (const float*)d_in[0];   // (N, N) float32
    float* out = (float*)d_out;                  // N*N adj ++ N zeros

    const size_t NN = 4096ull * 4096ull;

    // Output 0: adj pass-through (device-to-device, async on stream —
    // graph-capture safe).
    hipMemcpyAsync(out, adj, NN * sizeof(float),
                   hipMemcpyDeviceToDevice, stream);

    // Output 1: exactly zero (log_softmax over singleton axis).
    hipMemsetAsync(out + NN, 0, 4096 * sizeof(float), stream);
}

// Round 2
// 25.717 us; speedup vs baseline: 1.0059x; 1.0059x over previous
//
#include <hip/hip_runtime.h>

// GATconv_72464688218548 — outputs are (adj, log_softmax(elu(...), axis=1))
// where the second output has shape (4096, 1): log_softmax over a singleton
// axis is identically 0 for any finite input. So:
//   d_out[0 : N*N]      = adj   (67 MB pass-through)
//   d_out[N*N : N*N+N]  = 0
// Single fused vectorized copy kernel; pure HBM-bound (134 MB round trip).

#define NN_F4 (4096ull * 4096ull / 4ull)   // 4,194,304 float4 elements
#define TAIL_F4 (4096ull / 4ull)           // 1,024 float4 of zeros

__global__ __launch_bounds__(256) void gat_copy_kernel(
    const float4* __restrict__ adj, float4* __restrict__ out) {
    const size_t stride = (size_t)gridDim.x * blockDim.x;
    size_t i = (size_t)blockIdx.x * blockDim.x + threadIdx.x;

    // Zero tail: first 1024 threads of the grid handle out2 = zeros(4096).
    if (i < TAIL_F4) {
        out[NN_F4 + i] = make_float4(0.f, 0.f, 0.f, 0.f);
    }

    // Grid-stride float4 copy of adj -> out.
    for (; i < NN_F4; i += stride) {
        out[i] = adj[i];
    }
}

extern "C" void kernel_launch(void* const* d_in, const int* in_sizes, int n_in,
                              void* d_out, int out_size, void* d_ws, size_t ws_size,
                              hipStream_t stream) {
    const float4* adj = (const float4*)d_in[0];
    float4* out = (float4*)d_out;

    // 2048 blocks x 256 threads = 524,288 threads; 8 float4/thread.
    gat_copy_kernel<<<2048, 256, 0, stream>>>(adj, out);
}